// Round 11
// baseline (247.790 us; speedup 1.0000x reference)
//
#include <hip/hip_runtime.h>
#include <math.h>

#define HW 4096   // H*W = 64*64; B=4, C=64, H=W=64, L=4096

typedef short bf16x8 __attribute__((ext_vector_type(8)));
typedef float floatx4 __attribute__((ext_vector_type(4)));
typedef unsigned short u16x8 __attribute__((ext_vector_type(8)));

__device__ __forceinline__ unsigned short f2bf_rne(float x) {
    unsigned int u = __float_as_uint(x);
    unsigned int r = (u + 0x7FFFu + ((u >> 16) & 1u)) >> 16;
    return (unsigned short)r;
}
__device__ __forceinline__ float bf2f(unsigned short h) {
    return __uint_as_float(((unsigned int)h) << 16);
}

// async global->LDS, 16 B per lane; LDS dest is wave-uniform base + lane*16.
__device__ __forceinline__ void gload_lds16(const void* gptr, void* lptr) {
    auto g = (const __attribute__((address_space(1))) unsigned int*)(unsigned long long)(gptr);
    auto l = (__attribute__((address_space(3))) unsigned int*)(unsigned int)(unsigned long long)(lptr);
    __builtin_amdgcn_global_load_lds(g, l, 16, 0, 0);
}

// ---------------- prep: z=0 Q / z=1 K: split fp32 -> bf16 (hi,lo), transpose
// to [p][c], fused per-pixel squared norms. Row layout (192 shorts):
//   Aq[b][p] = [Qh | UNINIT | Ql],  Bq[b][p] = [Kh | Kl | UNINIT]
// (readers use only A slices {0,2} / B slices {0,1}).
// z=2: transpose V -> VT[b][p][c] (f32) so gatherT reads channels contiguous.
__global__ __launch_bounds__(256)
void prep_kernel(const float* __restrict__ Q, const float* __restrict__ K,
                 const float* __restrict__ V,
                 unsigned short* __restrict__ Aq, unsigned short* __restrict__ Bq,
                 float* __restrict__ VT,
                 float* __restrict__ pix2q, float* __restrict__ pix2k) {
    __shared__ float sT[64][65];
    const int tid = threadIdx.x;
    const int p0 = blockIdx.x * 64;
    const int b = blockIdx.y;
    const int which = blockIdx.z;            // 0=Q, 1=K, 2=V
    const float* __restrict__ src = (which == 0) ? Q : ((which == 1) ? K : V);

#pragma unroll
    for (int it = 0; it < 16; ++it) {
        int idx = it * 256 + tid;
        int c = idx >> 6, x = idx & 63;
        sT[c][x] = src[((size_t)b * 64 + c) * HW + p0 + x];
    }
    __syncthreads();
    const int pp = tid >> 2, qt = tid & 3;

    if (which == 2) {                        // V: pure f32 transpose
        float* dst = VT + ((size_t)b * 4096 + p0 + pp) * 64 + qt * 16;
#pragma unroll
        for (int j = 0; j < 4; ++j) {
            float4 v = make_float4(sT[qt * 16 + 4 * j + 0][pp], sT[qt * 16 + 4 * j + 1][pp],
                                   sT[qt * 16 + 4 * j + 2][pp], sT[qt * 16 + 4 * j + 3][pp]);
            *(float4*)(dst + 4 * j) = v;
        }
        return;
    }

    const int isK = which;
    unsigned short* __restrict__ dst = isK ? Bq : Aq;
    float* __restrict__ pix2 = isK ? pix2k : pix2q;
    const size_t base = ((size_t)b * 4096 + p0 + pp) * 192;
    {
        float sq = 0.f;
        u16x8 hv[2], lv[2];
#pragma unroll
        for (int g = 0; g < 2; ++g)
#pragma unroll
            for (int j = 0; j < 8; ++j) {
                int c = qt * 16 + g * 8 + j;
                float x = sT[c][pp];
                sq = fmaf(x, x, sq);
                unsigned short h = f2bf_rne(x);
                hv[g][j] = h;
                lv[g][j] = f2bf_rne(x - bf2f(h));
            }
        sq += __shfl_xor(sq, 1, 64);
        sq += __shfl_xor(sq, 2, 64);
        if (qt == 0) pix2[(b << 12) + p0 + pp] = sq;
#pragma unroll
        for (int g = 0; g < 2; ++g) {
            int co = qt * 16 + g * 8;
            *(u16x8*)(dst + base + co)                     = hv[g];  // hi slice
            *(u16x8*)(dst + base + (isK ? 64 : 128) + co)  = lv[g];  // lo slice
        }
    }
}

// ---------------- fused MFMA GEMM (K=576: y-3sum in K) + x-3sum + argmax -----
// 256x256 tile, 16 waves (1024 thr), wave tile 64(q) x 64(k): acc = 64 VGPR
// (R7/R8's 8-wave/128-VGPR-acc variant spilled ~48 regs; this one fits).
// LDS: 4 classes (A-hi, A-lo, B-hi, B-lo) x 5-slot rings of 64-row chunks
// (8 KB) = 160 KB; chunk c -> slot c%5; counted vmcnt, never 0 mid-loop.
// Per (dy,kk): af=Ah, bh=Bh: S0=MM16(af,bh); bl=Bl: S1=MM16(af,bl);
// al=Al: S2=MM16(al,bh).  All frag sets intra-step -> no cross-step caches.
// Staging by waves 0-7 only (512 lanes x 16 B = one 8 KB chunk per class).
// rnk computed inline from pix2k.
#define WAITV(n_) asm volatile("s_waitcnt vmcnt(" #n_ ")" ::: "memory")
#define SB do { __builtin_amdgcn_s_barrier(); asm volatile("" ::: "memory"); } while (0)

#define AHB 0
#define ALB 40960
#define BHB 81920
#define BLB 122880

#define ISSUE4(c_) do { if (issuer) { \
    const size_t ro_ = (size_t)((c_) * 64 + rr) * 384; \
    gload_lds16(agb + ro_ +   0 + G16, smem + AHB + ((c_) % 5) * 8192 + t16); \
    gload_lds16(agb + ro_ + 256 + G16, smem + ALB + ((c_) % 5) * 8192 + t16); \
    gload_lds16(bgb + ro_ +   0 + G16, smem + BHB + ((c_) % 5) * 8192 + t16); \
    gload_lds16(bgb + ro_ + 128 + G16, smem + BLB + ((c_) % 5) * 8192 + t16); \
} } while (0)

#define GISS4(c_) do { if (issuer) { \
    const ptrdiff_t ro_ = (ptrdiff_t)((c_) * 64 + rr) * 384; \
    uint4 ah_ = make_uint4(0u,0u,0u,0u), al_ = ah_, bh_ = ah_, bl_ = ah_; \
    if ((unsigned)(arow + (c_) * 64 + rr) < 4096u) { \
        ah_ = *(const uint4*)(agb + ro_ + G16); \
        al_ = *(const uint4*)(agb + ro_ + 256 + G16); } \
    if ((unsigned)(brow + (c_) * 64 + rr) < 4096u) { \
        bh_ = *(const uint4*)(bgb + ro_ + G16); \
        bl_ = *(const uint4*)(bgb + ro_ + 128 + G16); } \
    *(uint4*)(smem + AHB + ((c_) % 5) * 8192 + t16) = ah_; \
    *(uint4*)(smem + ALB + ((c_) % 5) * 8192 + t16) = al_; \
    *(uint4*)(smem + BHB + ((c_) % 5) * 8192 + t16) = bh_; \
    *(uint4*)(smem + BLB + ((c_) % 5) * 8192 + t16) = bl_; \
} } while (0)

#define MM16(af_, bf_) do { \
    __builtin_amdgcn_s_setprio(1); \
    _Pragma("unroll") \
    for (int mt_ = 0; mt_ < 4; ++mt_) \
        _Pragma("unroll") \
        for (int nt_ = 0; nt_ < 4; ++nt_) \
            acc[mt_][nt_] = __builtin_amdgcn_mfma_f32_16x16x32_bf16( \
                (af_)[mt_], (bf_)[nt_], acc[mt_][nt_], 0, 0, 0); \
    __builtin_amdgcn_s_setprio(0); \
} while (0)

#define LD4(dst_, base_, pk_) do { \
    _Pragma("unroll") \
    for (int q_ = 0; q_ < 4; ++q_) \
        (dst_)[q_] = *(const bf16x8*)((base_) + q_ * 2048 + (pk_)); \
} while (0)

#define DY_STEP(dy_) do { \
    const char* Ahs_ = smem + AHB + ((wm2 + (dy_)) % 5) * 8192 + rowB; \
    const char* Als_ = smem + ALB + ((wm2 + (dy_)) % 5) * 8192 + rowB; \
    const char* Bhs_ = smem + BHB + ((wn  + (dy_)) % 5) * 8192 + rowB; \
    const char* Bls_ = smem + BLB + ((wn  + (dy_)) % 5) * 8192 + rowB; \
    _Pragma("unroll 1") \
    for (int kk = 0; kk < 2; ++kk) { \
        const int pk_ = kk ? posK1 : posK0; \
        bf16x8 af[4], bh[4], t4[4]; \
        LD4(af, Ahs_, pk_); \
        LD4(bh, Bhs_, pk_); \
        MM16(af, bh); \
        LD4(t4, Bls_, pk_); \
        MM16(af, t4); \
        LD4(t4, Als_, pk_); \
        MM16(t4, bh); \
    } \
} while (0)

__global__ __launch_bounds__(1024, 4)
void gemm_fused_kernel(const unsigned short* __restrict__ Aq, const unsigned short* __restrict__ Bq,
                       const float* __restrict__ pix2k,
                       float* __restrict__ part_val, int* __restrict__ part_arg) {
    __shared__ __align__(16) char smem[163840];
    const int tid = threadIdx.x;
    const int lane = tid & 63, wid = tid >> 6;
    const int m15 = lane & 15, quad = lane >> 4;
    const int wn = wid & 3, wm2 = wid >> 2;   // wave grid: 4(q) x 4(k)
    // XCD swizzle: per-b 256 wgs; XCD x owns 2 q-supertiles x all 16 k-tiles.
    const int f = blockIdx.x;
    const int o = ((f & 7) << 5) + (f >> 3);
    const int kt = o & 15, qt = o >> 4;
    const int k0 = kt << 8, q0 = qt << 8;
    const int b = blockIdx.y;
    const int arow = q0 - 64, brow = k0 - 64;
    const char* agb = (const char*)(Aq + (size_t)b * 4096 * 192) + (ptrdiff_t)arow * 384;
    const char* bgb = (const char*)(Bq + (size_t)b * 4096 * 192) + (ptrdiff_t)brow * 384;
    const bool aInt = (q0 >= 64) && (q0 + 320 <= 4096);
    const bool bInt = (k0 >= 64) && (k0 + 320 <= 4096);

    // staging (waves 0-7 = tid<512): one 8 KB chunk per class per ISSUE4
    const bool issuer = tid < 512;
    const int rr = tid >> 3;                 // 0..63 for issuers
    const int G16 = ((tid & 7) ^ (rr & 7)) * 16;
    const int t16 = tid * 16;                // 0..8191 for issuers
    // fragment-read offsets (row&7 == m15&7 for rows m15+16*mt)
    const int rowB = m15 * 128;
    const int posK0 = (quad ^ (m15 & 7)) * 16;
    const int posK1 = ((4 + quad) ^ (m15 & 7)) * 16;

    floatx4 acc[4][4];
#pragma unroll
    for (int i = 0; i < 4; ++i)
#pragma unroll
        for (int j = 0; j < 4; ++j) acc[i][j] = (floatx4)0.f;

    if (aInt && bInt) {
        ISSUE4(0); ISSUE4(1); ISSUE4(2); ISSUE4(3);  // dy0 set (16 loads/issuer)
        ISSUE4(4);                                    // +4: needed at dy1
        WAITV(4); SB;                                 // chunks 0..3 ready
        DY_STEP(0);                                   // slots {0..3}
        SB;                                           // slot-0 readers done
        ISSUE4(5);                                    // chunk 5 -> slot 0
        WAITV(4); SB;                                 // chunk 4 ready
        DY_STEP(1);                                   // slots {1..4}
        WAITV(0); SB;                                 // chunk 5 ready
        DY_STEP(2);                                   // slots {2,3,4,0}
    } else {
        // guarded boundary path: same slots, predicated uint4 + ds_write
        GISS4(0); GISS4(1); GISS4(2); GISS4(3); GISS4(4);
        __syncthreads();
        DY_STEP(0);
        __syncthreads();
        GISS4(5);
        __syncthreads();
        DY_STEP(1);
        DY_STEP(2);          // no LDS writes since DY_STEP(1) -> no barrier
    }
    __syncthreads();         // rings dead before epilogue overwrites

    // ---- epilogue: four 64-row phases; x-3sum + argmax over the 256-k tile;
    // cross-wave LDS reduce -> 1 partial per (block, q).  rnk inline. ----
    float* Csh = (float*)smem;               // [64][261] = 66816 B
    float* bvs = (float*)(smem + 66816);     // [16][64]
    int*   bas = (int*)(smem + 70912);       // [16][64]
    float* Lrnk = (float*)(smem + 75008);    // [256]
    if (tid < 256) {                         // rnk for k0..k0+255 (4 image rows)
        int k = k0 + tid;
        int py = k >> 6, px = k & 63;
        float sk = 0.f;
        for (int dy = -1; dy <= 1; ++dy)
            for (int dx = -1; dx <= 1; ++dx) {
                int yy = py + dy, xx = px + dx;
                if ((unsigned)yy < 64u && (unsigned)xx < 64u)
                    sk += pix2k[(b << 12) + (yy << 6) + xx];
            }
        Lrnk[tid] = 1.f / fmaxf(sqrtf(sk), 1e-12f);
    }
    const int q_l = tid & 63;
    const int qr = tid >> 6;                 // k-sixteenth (0..15), one per wave
    const int c0 = qr * 16;
    const float4 zero4 = make_float4(0.f, 0.f, 0.f, 0.f);

#pragma unroll
    for (int h = 0; h < 4; ++h) {
        if (h) __syncthreads();              // prev-phase readers done
        if (wm2 == h) {
#pragma unroll
            for (int mt = 0; mt < 4; ++mt)
#pragma unroll
                for (int nt = 0; nt < 4; ++nt)
#pragma unroll
                    for (int j = 0; j < 4; ++j)
                        Csh[(mt * 16 + quad * 4 + j) * 261 + (wn << 6) + nt * 16 + m15] =
                            acc[mt][nt][j];
        }
        __syncthreads();                     // also orders Lrnk writes (h==0)

        const bool qm = q_l > 0;             // qx>0: diag- allowed
        const bool qp = q_l < 63;            // qx<63: diag+ allowed
        const float* rC = Csh + q_l * 261;
        const float* rM = Csh + (q_l - 1) * 261;
        const float* rP = Csh + (q_l + 1) * 261;
        float4 prevm = (qm && c0 > 0) ? *(const float4*)&rM[c0 - 4] : zero4;
        float4 rpj   = qp ? *(const float4*)&rP[c0] : zero4;
        float bv = -INFINITY;
        int ba = 0;
#pragma unroll
        for (int j = 0; j < 4; ++j) {
            int c = c0 + 4 * j;
            float4 cen = *(const float4*)&rC[c];
            float4 rm4 = qm ? *(const float4*)&rM[c] : zero4;
            float4 rp1 = (qp && (c + 4) < 256) ? *(const float4*)&rP[c + 4] : zero4;
            float4 o4;
            o4.x = cen.x + (((c & 63) != 0) ? prevm.w : 0.f) + rpj.y;
            o4.y = cen.y + rm4.x + rpj.z;
            o4.z = cen.z + rm4.y + rpj.w;
            o4.w = cen.w + rm4.z + ((((c + 3) & 63) != 63) ? rp1.x : 0.f);
            float4 rk = *(const float4*)&Lrnk[c];
            // ascending k + strict > = first-occurrence argmax
            float v0 = o4.x * rk.x; if (v0 > bv) { bv = v0; ba = k0 + c + 0; }
            float v1 = o4.y * rk.y; if (v1 > bv) { bv = v1; ba = k0 + c + 1; }
            float v2 = o4.z * rk.z; if (v2 > bv) { bv = v2; ba = k0 + c + 2; }
            float v3 = o4.w * rk.w; if (v3 > bv) { bv = v3; ba = k0 + c + 3; }
            prevm = rm4;
            rpj = rp1;
        }
        bvs[(qr << 6) + q_l] = bv;
        bas[(qr << 6) + q_l] = ba;
        __syncthreads();
        if (tid < 64) {
            float v = bvs[tid];
            int a = bas[tid];
#pragma unroll
            for (int s = 1; s < 16; ++s) {   // ascending sixteenth = ascending k
                float v2 = bvs[(s << 6) + tid];
                if (v2 > v) { v = v2; a = bas[(s << 6) + tid]; }
            }
            int q = q0 + (h << 6) + tid;
            part_val[(((b << 4) + kt) << 12) + q] = v;
            part_arg[(((b << 4) + kt) << 12) + q] = a;
        }
    }
}

// ---------------- gather + fold + fused combine + S ----------------
// Per block (y, b, cg): combine the 16 k-slot partials for arg rows y-1..y+1
// (ascending s = ascending k -> first-occurrence argmax), write S for row y
// (cg==0; rnq inline from pix2q), then T[c,y,x] = (1/9) sum_9 VT[a(q)+d][c].
__global__ __launch_bounds__(256)
void gatherT_kernel(const float* __restrict__ VT,
                    const float* __restrict__ part_val, const int* __restrict__ part_arg,
                    const float* __restrict__ pix2q,
                    float* __restrict__ S_out, float* __restrict__ T_out) {
    __shared__ int sArg[192];
    const int y = blockIdx.x, b = blockIdx.y, cg = blockIdx.z;
    const int tid = threadIdx.x;
    if (tid < 192) {
        int r = tid >> 6, x = tid & 63;
        int yy = y - 1 + r;
        int a = 0;
        if ((unsigned)yy < 64u) {
            int base = (b << 16) + (yy << 6) + x;   // part[(b*16+s)][q]
            float bv = -INFINITY; int ba = 0;
#pragma unroll
            for (int s = 0; s < 16; ++s) {   // ascending s = ascending k
                float v = part_val[base + (s << 12)];
                int aa = part_arg[base + (s << 12)];
                if (v > bv) { bv = v; ba = aa; }
            }
            a = ba;
            if (r == 1 && cg == 0) {         // S for row y, rnq inline
                float sq = 0.f;
                for (int dy = -1; dy <= 1; ++dy)
                    for (int dx = -1; dx <= 1; ++dx) {
                        int y2 = yy + dy, x2 = x + dx;
                        if ((unsigned)y2 < 64u && (unsigned)x2 < 64u)
                            sq += pix2q[(b << 12) + (y2 << 6) + x2];
                    }
                S_out[(b << 12) + (yy << 6) + x] =
                    bv * (1.f / fmaxf(sqrtf(sq), 1e-12f));
            }
        }
        sArg[tid] = a;
    }
    __syncthreads();

    const int x = tid >> 2, cq = tid & 3;
    const float* Vb = VT + (size_t)b * 4096 * 64 + cg * 16 + cq * 4;
    float ax = 0.f, ay = 0.f, az = 0.f, aw = 0.f;
#pragma unroll
    for (int t = 0; t < 9; ++t) {
        int dy = t / 3 - 1, dx = t % 3 - 1;
        int qy = y - dy, qx = x - dx;
        if ((unsigned)qy < 64u && (unsigned)qx < 64u) {
            int a = sArg[(1 - dy) * 64 + qx];
            int sy = (a >> 6) + dy, sx = (a & 63) + dx;
            if ((unsigned)sy < 64u && (unsigned)sx < 64u) {
                float4 v = *(const float4*)(Vb + (size_t)((sy << 6) + sx) * 64);
                ax += v.x; ay += v.y; az += v.z; aw += v.w;
            }
        }
    }
    float* Tb = T_out + ((size_t)b * 64 + cg * 16 + cq * 4) * HW + (y << 6) + x;
    Tb[0]          = ax * (1.f / 9.f);
    Tb[HW]         = ay * (1.f / 9.f);
    Tb[2 * HW]     = az * (1.f / 9.f);
    Tb[3 * HW]     = aw * (1.f / 9.f);
}

extern "C" void kernel_launch(void* const* d_in, const int* in_sizes, int n_in,
                              void* d_out, int out_size, void* d_ws, size_t ws_size,
                              hipStream_t stream) {
    const float* V = (const float*)d_in[0];
    const float* K = (const float*)d_in[1];
    const float* Q = (const float*)d_in[2];
    float* S_out = (float*)d_out;            // 4*4096
    float* T_out = S_out + 4 * HW;           // 4*64*4096

    char* ws = (char*)d_ws;
    float* pix2q = (float*)(ws + 0);                 // 64 KB
    float* pix2k = (float*)(ws + 65536);             // 64 KB
    float* part_val = (float*)(ws + 262144);         // 4*16*4096 f = 1 MB used
    int*   part_arg = (int*)(ws + 8650752);          // 1 MB used
    float* VT    = (float*)(ws + 10747904);          // 4*4096*64 f32 = 4 MiB
    unsigned short* Aq = (unsigned short*)(ws + 17039360);   // 4*4096*192 bf16 = 6 MiB
    unsigned short* Bq = (unsigned short*)(ws + 23330816);   // 6 MiB

    prep_kernel<<<dim3(64, 4, 3), 256, 0, stream>>>(Q, K, V, Aq, Bq, VT, pix2q, pix2k);
    gemm_fused_kernel<<<dim3(256, 4), 1024, 0, stream>>>(Aq, Bq, pix2k, part_val, part_arg);
    gatherT_kernel<<<dim3(64, 4, 4), 256, 0, stream>>>(VT, part_val, part_arg, pix2q, S_out, T_out);
}

// Round 12
// 190.508 us; speedup vs baseline: 1.3007x; 1.3007x over previous
//
#include <hip/hip_runtime.h>
#include <math.h>

#define HW 4096   // H*W = 64*64; B=4, C=64, H=W=64, L=4096

typedef short bf16x8 __attribute__((ext_vector_type(8)));
typedef float floatx4 __attribute__((ext_vector_type(4)));
typedef unsigned short u16x8 __attribute__((ext_vector_type(8)));

__device__ __forceinline__ unsigned short f2bf_rne(float x) {
    unsigned int u = __float_as_uint(x);
    unsigned int r = (u + 0x7FFFu + ((u >> 16) & 1u)) >> 16;
    return (unsigned short)r;
}
__device__ __forceinline__ float bf2f(unsigned short h) {
    return __uint_as_float(((unsigned int)h) << 16);
}

// async global->LDS, 16 B per lane; LDS dest is wave-uniform base + lane*16.
__device__ __forceinline__ void gload_lds16(const void* gptr, void* lptr) {
    auto g = (const __attribute__((address_space(1))) unsigned int*)(unsigned long long)(gptr);
    auto l = (__attribute__((address_space(3))) unsigned int*)(unsigned int)(unsigned long long)(lptr);
    __builtin_amdgcn_global_load_lds(g, l, 16, 0, 0);
}

// ---------------- prep: z=0 Q / z=1 K: split fp32 -> bf16 (hi,lo), transpose
// to [p][c], fused per-pixel squared norms. Row layout (192 shorts):
//   Aq[b][p] = [Qh | UNINIT | Ql],  Bq[b][p] = [Kh | Kl | UNINIT]
// (readers use only A slices {0,2} / B slices {0,1}).
// z=2: transpose V -> VT[b][p][c] (f32) so gatherT reads channels contiguous.
__global__ __launch_bounds__(256)
void prep_kernel(const float* __restrict__ Q, const float* __restrict__ K,
                 const float* __restrict__ V,
                 unsigned short* __restrict__ Aq, unsigned short* __restrict__ Bq,
                 float* __restrict__ VT,
                 float* __restrict__ pix2q, float* __restrict__ pix2k) {
    __shared__ float sT[64][65];
    const int tid = threadIdx.x;
    const int p0 = blockIdx.x * 64;
    const int b = blockIdx.y;
    const int which = blockIdx.z;            // 0=Q, 1=K, 2=V
    const float* __restrict__ src = (which == 0) ? Q : ((which == 1) ? K : V);

#pragma unroll
    for (int it = 0; it < 16; ++it) {
        int idx = it * 256 + tid;
        int c = idx >> 6, x = idx & 63;
        sT[c][x] = src[((size_t)b * 64 + c) * HW + p0 + x];
    }
    __syncthreads();
    const int pp = tid >> 2, qt = tid & 3;

    if (which == 2) {                        // V: pure f32 transpose
        float* dst = VT + ((size_t)b * 4096 + p0 + pp) * 64 + qt * 16;
#pragma unroll
        for (int j = 0; j < 4; ++j) {
            float4 v = make_float4(sT[qt * 16 + 4 * j + 0][pp], sT[qt * 16 + 4 * j + 1][pp],
                                   sT[qt * 16 + 4 * j + 2][pp], sT[qt * 16 + 4 * j + 3][pp]);
            *(float4*)(dst + 4 * j) = v;
        }
        return;
    }

    const int isK = which;
    unsigned short* __restrict__ dst = isK ? Bq : Aq;
    float* __restrict__ pix2 = isK ? pix2k : pix2q;
    const size_t base = ((size_t)b * 4096 + p0 + pp) * 192;
    {
        float sq = 0.f;
        u16x8 hv[2], lv[2];
#pragma unroll
        for (int g = 0; g < 2; ++g)
#pragma unroll
            for (int j = 0; j < 8; ++j) {
                int c = qt * 16 + g * 8 + j;
                float x = sT[c][pp];
                sq = fmaf(x, x, sq);
                unsigned short h = f2bf_rne(x);
                hv[g][j] = h;
                lv[g][j] = f2bf_rne(x - bf2f(h));
            }
        sq += __shfl_xor(sq, 1, 64);
        sq += __shfl_xor(sq, 2, 64);
        if (qt == 0) pix2[(b << 12) + p0 + pp] = sq;
#pragma unroll
        for (int g = 0; g < 2; ++g) {
            int co = qt * 16 + g * 8;
            *(u16x8*)(dst + base + co)                     = hv[g];  // hi slice
            *(u16x8*)(dst + base + (isK ? 64 : 128) + co)  = lv[g];  // lo slice
        }
    }
}

// ---------------- fused MFMA GEMM (K=576: y-3sum in K) + x-3sum + argmax -----
// 128x128 tile, 8 waves (512 thr), wave tile 64(q) x 32(k): acc = 32 regs.
// (Occupancy play: 2 blocks/CU x 8 waves = 4 waves/SIMD, vs 2 for the 4-wave
// version; reg law from R7/R8/R11: unified cap = 512/min-waves-EU, acc+temps
// must fit. Here 32 + ~75 fits the 128 cap at (512,4).)
// 3 mega-steps (one per dy); per kk: s0=Qh.Kh (cache afc,bfc), s1=Qh.Kl
// (afc reg, Bl LDS), s2=Ql.Kh (Al LDS, bfc reg). Kh'/Al-unused never staged.
// Rings: A 5 slots {Ah0@0,Ah1@1,Ah2@4,Ah3@2; Al0@2,Al1@3,Al2@0,Al3@3},
//        B 5 slots {Bh0@0,Bh1@1,Bh2@4,Bh3@2; Bl0@2,Bl1@3,Bl2@0,Bl3@3}.
// Hand-verified: every overwrite is post-barrier of its slot's last reader;
// every read is behind a counted-vmcnt retire. 1 gload/thread/chunk.
#define WAITV(n_) asm volatile("s_waitcnt vmcnt(" #n_ ")" ::: "memory")
#define PBAR(n_) do { WAITV(n_); __builtin_amdgcn_s_barrier(); \
                      asm volatile("" ::: "memory"); } while (0)
#define SB do { __builtin_amdgcn_s_barrier(); asm volatile("" ::: "memory"); } while (0)

#define ISSUE_A(c_, sg_, slot_) \
    gload_lds16(agb + (size_t)((c_) * 64 + rr) * 384 + (sg_) * 128 + G16, \
                smem + (slot_) * 8192 + t16)
#define ISSUE_B(c_, sg_, slot_) \
    gload_lds16(bgb + (size_t)((c_) * 64 + rr) * 384 + (sg_) * 128 + G16, \
                smemB + (slot_) * 8192 + t16)

#define GISS_A(c_, sg_, slot_) do { \
    uint4 v_ = make_uint4(0u, 0u, 0u, 0u); \
    if ((unsigned)(arow + (c_) * 64 + rr) < 4096u) \
        v_ = *(const uint4*)(agb + (ptrdiff_t)((c_) * 64 + rr) * 384 + (sg_) * 128 + G16); \
    *(uint4*)(smem + (slot_) * 8192 + t16) = v_; \
} while (0)
#define GISS_B(c_, sg_, slot_) do { \
    uint4 v_ = make_uint4(0u, 0u, 0u, 0u); \
    if ((unsigned)(brow + (c_) * 64 + rr) < 4096u) \
        v_ = *(const uint4*)(bgb + (ptrdiff_t)((c_) * 64 + rr) * 384 + (sg_) * 128 + G16); \
    *(uint4*)(smemB + (slot_) * 8192 + t16) = v_; \
} while (0)

#define MM8(af_, bf_) do { \
    __builtin_amdgcn_s_setprio(1); \
    _Pragma("unroll") \
    for (int mt_ = 0; mt_ < 4; ++mt_) \
        _Pragma("unroll") \
        for (int nt_ = 0; nt_ < 2; ++nt_) \
            acc[mt_][nt_] = __builtin_amdgcn_mfma_f32_16x16x32_bf16( \
                (af_)[mt_], (bf_)[nt_], acc[mt_][nt_], 0, 0, 0); \
    __builtin_amdgcn_s_setprio(0); \
} while (0)

#define DY_MEGA(dy_) do { \
    const char* AhS_ = smem + ahS[wm + (dy_)] * 8192 + rowB; \
    const char* AlS_ = smem + alS[wm + (dy_)] * 8192 + rowB; \
    const char* BhS_ = smemB + bhS[wnC + (dy_)] * 8192 + rowBB; \
    const char* BlS_ = smemB + blS[wnC + (dy_)] * 8192 + rowBB; \
    _Pragma("unroll 1") \
    for (int kk = 0; kk < 2; ++kk) { \
        const int pk_ = kk ? posK1 : posK0; \
        bf16x8 afc[4], bfc[2], t4[4]; \
        _Pragma("unroll") \
        for (int mt = 0; mt < 4; ++mt) \
            afc[mt] = *(const bf16x8*)(AhS_ + mt * 2048 + pk_); \
        _Pragma("unroll") \
        for (int nt = 0; nt < 2; ++nt) \
            bfc[nt] = *(const bf16x8*)(BhS_ + nt * 2048 + pk_); \
        MM8(afc, bfc); \
        _Pragma("unroll") \
        for (int nt = 0; nt < 2; ++nt) \
            t4[nt] = *(const bf16x8*)(BlS_ + nt * 2048 + pk_); \
        MM8(afc, t4); \
        _Pragma("unroll") \
        for (int mt = 0; mt < 4; ++mt) \
            t4[mt] = *(const bf16x8*)(AlS_ + mt * 2048 + pk_); \
        MM8(t4, bfc); \
    } \
} while (0)

__global__ __launch_bounds__(512, 4)
void gemm_fused_kernel(const unsigned short* __restrict__ Aq, const unsigned short* __restrict__ Bq,
                       const float* __restrict__ pix2k,
                       float* __restrict__ part_val, int* __restrict__ part_arg) {
    __shared__ __align__(16) char smem[81920];   // A 5x8K | B 5x8K; epilogue aliases A region
    char* const smemB = smem + 40960;
    const int tid = threadIdx.x;
    const int lane = tid & 63, wid = tid >> 6;
    const int m15 = lane & 15, quad = lane >> 4;
    const int wm = wid & 1;                  // q half (64 rows)
    const int wn2 = wid >> 1;                // k quarter (32 cols), 0..3
    const int wnC = wn2 >> 1, wnF = wn2 & 1; // B chunk half / frag pair
    // chunk -> slot maps (see header comment)
    const int ahS[4] = {0, 1, 4, 2};
    const int alS[4] = {2, 3, 0, 3};
    const int bhS[4] = {0, 1, 4, 2};
    const int blS[4] = {2, 3, 0, 3};
    // XCD-chunked swizzle: per-b 1024 wgs; XCD x owns 4 q-tiles x 32 k-tiles.
    const int f = blockIdx.x + (blockIdx.y << 5);
    const int o = ((f & 7) << 7) + (f >> 3);
    const int kt = o & 31, qt = o >> 5;
    const int k0 = kt << 7;
    const int q0 = qt << 7;
    const int b = blockIdx.z;
    const int arow = q0 - 64, brow = k0 - 64;
    const char* agb = (const char*)(Aq + (size_t)b * 4096 * 192) + (ptrdiff_t)arow * 384;
    const char* bgb = (const char*)(Bq + (size_t)b * 4096 * 192) + (ptrdiff_t)brow * 384;
    const bool aInt = (q0 >= 64) && (q0 <= 4096 - 192);
    const bool bInt = (k0 >= 64) && (k0 <= 4096 - 192);

    // staging: 512 thr x 16 B = one 8 KB chunk per issue (1 gload/thread)
    const int rr = tid >> 3;
    const int G16 = ((tid & 7) ^ (rr & 7)) * 16;
    const int t16 = tid * 16;
    // fragment-read offsets (row&7 == m15&7 for all frag rows)
    const int rowB = m15 * 128;
    const int rowBB = (wnF * 32 + m15) * 128;
    const int posK0 = (quad ^ (m15 & 7)) * 16;
    const int posK1 = ((4 + quad) ^ (m15 & 7)) * 16;

    floatx4 acc[4][2];
#pragma unroll
    for (int i = 0; i < 4; ++i)
#pragma unroll
        for (int j = 0; j < 2; ++j) acc[i][j] = (floatx4)0.f;

    if (aInt && bInt) {
        // prologue (10 chunks): Ah0@0 Ah1@1 Bh0@0 Bh1@1 Al0@2 Al1@3 Bl0@2
        // Bl1@3 Ah2@4 Bh2@4
        ISSUE_A(0, 0, 0); ISSUE_A(1, 0, 1); ISSUE_B(0, 0, 0); ISSUE_B(1, 0, 1);
        ISSUE_A(0, 2, 2); ISSUE_A(1, 2, 3); ISSUE_B(0, 1, 2); ISSUE_B(1, 1, 3);
        ISSUE_A(2, 0, 4); ISSUE_B(2, 0, 4);
        PBAR(2);                 // retire first 8 = dy0 working set
        DY_MEGA(0);
        SB;                      // dy0 readers done -> slots 0(A),0(B),2(A),2(B) free
        ISSUE_A(2, 2, 0);        // Al2 -> A slot 0
        ISSUE_B(2, 1, 0);        // Bl2 -> B slot 0
        ISSUE_A(3, 0, 2);        // Ah3 -> A slot 2
        ISSUE_B(3, 0, 2);        // Bh3 -> B slot 2
        PBAR(2);                 // retire Ah2,Bh2,Al2,Bl2 (Ah3,Bh3 in flight)
        DY_MEGA(1);
        SB;                      // dy1 readers done -> slots 3(A),3(B) free
        ISSUE_A(3, 2, 3);        // Al3 -> A slot 3
        ISSUE_B(3, 1, 3);        // Bl3 -> B slot 3
        PBAR(0);                 // retire Ah3,Bh3,Al3,Bl3
        DY_MEGA(2);
    } else {
        // guarded boundary path: same slots, predicated uint4 + ds_write
        GISS_A(0, 0, 0); GISS_A(1, 0, 1); GISS_B(0, 0, 0); GISS_B(1, 0, 1);
        GISS_A(0, 2, 2); GISS_A(1, 2, 3); GISS_B(0, 1, 2); GISS_B(1, 1, 3);
        GISS_A(2, 0, 4); GISS_B(2, 0, 4);
        __syncthreads();
        DY_MEGA(0);
        __syncthreads();
        GISS_A(2, 2, 0); GISS_B(2, 1, 0); GISS_A(3, 0, 2); GISS_B(3, 0, 2);
        __syncthreads();
        DY_MEGA(1);
        __syncthreads();
        GISS_A(3, 2, 3); GISS_B(3, 1, 3);
        __syncthreads();
        DY_MEGA(2);
    }
    __syncthreads();   // rings dead before epilogue overwrites

    // ---- epilogue: inline rnk; two 64-row phases; x-3sum + argmax over the
    // 128-k tile; cross-wave LDS reduce -> one partial per (block, q) ----
    float* Csh = (float*)smem;               // [64][133] = 34048 B
    float* bvs = (float*)(smem + 34816);     // [8][64]
    int*   bas = (int*)(smem + 36864);       // [8][64]
    float* Lrnk = (float*)(smem + 38912);    // [128]
    if (tid < 128) {                         // rnk for k0..k0+127 (2 image rows)
        int k = k0 + tid;
        int py = k >> 6, px = k & 63;
        float sk = 0.f;
        for (int dy = -1; dy <= 1; ++dy)
            for (int dx = -1; dx <= 1; ++dx) {
                int yy = py + dy, xx = px + dx;
                if ((unsigned)yy < 64u && (unsigned)xx < 64u)
                    sk += pix2k[(b << 12) + (yy << 6) + xx];
            }
        Lrnk[tid] = 1.f / fmaxf(sqrtf(sk), 1e-12f);
    }
    const int q_l = tid & 63;
    const int qr = tid >> 6;                 // k-eighth (0..7), one per wave
    const int c0 = qr * 16;
    const float4 zero4 = make_float4(0.f, 0.f, 0.f, 0.f);

#pragma unroll
    for (int h = 0; h < 2; ++h) {
        if (h) __syncthreads();              // phase-0 readers done before overwrite
        if (wm == h) {
#pragma unroll
            for (int mt = 0; mt < 4; ++mt)
#pragma unroll
                for (int nt = 0; nt < 2; ++nt)
#pragma unroll
                    for (int j = 0; j < 4; ++j)
                        Csh[(mt * 16 + quad * 4 + j) * 133 + (wn2 << 5) + nt * 16 + m15] =
                            acc[mt][nt][j];
        }
        __syncthreads();                     // also orders Lrnk writes (h==0)

        const bool qm = q_l > 0;             // qx>0: diag- allowed
        const bool qp = q_l < 63;            // qx<63: diag+ allowed
        const float* rC = Csh + q_l * 133;
        const float* rM = Csh + (q_l - 1) * 133;
        const float* rP = Csh + (q_l + 1) * 133;
        float4 prevm = (qm && c0 > 0) ? *(const float4*)&rM[c0 - 4] : zero4;
        float4 rpj   = qp ? *(const float4*)&rP[c0] : zero4;
        float bv = -INFINITY;
        int ba = 0;
#pragma unroll
        for (int j = 0; j < 4; ++j) {
            int c = c0 + 4 * j;
            float4 cen = *(const float4*)&rC[c];
            float4 rm4 = qm ? *(const float4*)&rM[c] : zero4;
            float4 rp1 = (qp && (c + 4) < 128) ? *(const float4*)&rP[c + 4] : zero4;
            float4 o4;
            o4.x = cen.x + (((c & 63) != 0) ? prevm.w : 0.f) + rpj.y;
            o4.y = cen.y + rm4.x + rpj.z;
            o4.z = cen.z + rm4.y + rpj.w;
            o4.w = cen.w + rm4.z + ((((c + 3) & 63) != 63) ? rp1.x : 0.f);
            float4 rk = *(const float4*)&Lrnk[c];
            // ascending k + strict > = first-occurrence argmax
            float v0 = o4.x * rk.x; if (v0 > bv) { bv = v0; ba = k0 + c + 0; }
            float v1 = o4.y * rk.y; if (v1 > bv) { bv = v1; ba = k0 + c + 1; }
            float v2 = o4.z * rk.z; if (v2 > bv) { bv = v2; ba = k0 + c + 2; }
            float v3 = o4.w * rk.w; if (v3 > bv) { bv = v3; ba = k0 + c + 3; }
            prevm = rm4;
            rpj = rp1;
        }
        bvs[(qr << 6) + q_l] = bv;
        bas[(qr << 6) + q_l] = ba;
        __syncthreads();
        if (tid < 64) {
            float v = bvs[tid];
            int a = bas[tid];
#pragma unroll
            for (int s = 1; s < 8; ++s) {    // ascending eighth = ascending k
                float v2 = bvs[(s << 6) + tid];
                if (v2 > v) { v = v2; a = bas[(s << 6) + tid]; }
            }
            int q = q0 + h * 64 + tid;
            part_val[(((b << 5) + kt) << 12) + q] = v;
            part_arg[(((b << 5) + kt) << 12) + q] = a;
        }
    }
}

// ---------------- combine 32 k-slot partials -> final arg + S ----------------
__global__ __launch_bounds__(256)
void argcombine_kernel(const float* __restrict__ part_val, const int* __restrict__ part_arg,
                       const float* __restrict__ pix2q,
                       float* __restrict__ S_out, int* __restrict__ argF) {
    __shared__ float rv[4][64];
    __shared__ int ra[4][64];
    const int tid = threadIdx.x;
    const int qi = tid & 63, sg = tid >> 6;
    const int q = blockIdx.x * 64 + qi;
    const int b = blockIdx.y;
    const int base = (b << 17) + q;
    float bv = -INFINITY; int ba = 0;
#pragma unroll
    for (int i = 0; i < 8; ++i) {            // ascending s = ascending k
        int s = sg * 8 + i;
        float v = part_val[base + (s << 12)];
        int aa = part_arg[base + (s << 12)];
        if (v > bv) { bv = v; ba = aa; }
    }
    rv[sg][qi] = bv; ra[sg][qi] = ba;
    __syncthreads();
    if (tid < 64) {
        float v = rv[0][tid]; int a = ra[0][tid];
#pragma unroll
        for (int s = 1; s < 4; ++s) {        // ascending group: first max wins
            float v2 = rv[s][tid];
            if (v2 > v) { v = v2; a = ra[s][tid]; }
        }
        int py = blockIdx.x, px = tid;       // q = py*64 + px
        float sq = 0.f;
        for (int dy = -1; dy <= 1; ++dy)
            for (int dx = -1; dx <= 1; ++dx) {
                int y2 = py + dy, x2 = px + dx;
                if ((unsigned)y2 < 64u && (unsigned)x2 < 64u)
                    sq += pix2q[(b << 12) + (y2 << 6) + x2];
            }
        int idx = (b << 12) + (py << 6) + px;
        S_out[idx] = v * (1.f / fmaxf(sqrtf(sq), 1e-12f));
        argF[idx] = a;
    }
}

// ---------------- gather + fold: T[c,y,x] = (1/9) sum_9 VT[a(q)+d][c] --------
__global__ __launch_bounds__(256)
void gatherT_kernel(const float* __restrict__ VT, const int* __restrict__ argF,
                    float* __restrict__ T_out) {
    __shared__ int sArg[192];
    const int y = blockIdx.x, b = blockIdx.y, cg = blockIdx.z;
    const int tid = threadIdx.x;
    if (tid < 192) {
        int r = tid >> 6, x = tid & 63;
        int yy = y - 1 + r;
        sArg[tid] = ((unsigned)yy < 64u) ? argF[(b << 12) + (yy << 6) + x] : 0;
    }
    __syncthreads();

    const int x = tid >> 2, cq = tid & 3;
    const float* Vb = VT + (size_t)b * 4096 * 64 + cg * 16 + cq * 4;
    float ax = 0.f, ay = 0.f, az = 0.f, aw = 0.f;
#pragma unroll
    for (int t = 0; t < 9; ++t) {
        int dy = t / 3 - 1, dx = t % 3 - 1;
        int qy = y - dy, qx = x - dx;
        if ((unsigned)qy < 64u && (unsigned)qx < 64u) {
            int a = sArg[(1 - dy) * 64 + qx];
            int sy = (a >> 6) + dy, sx = (a & 63) + dx;
            if ((unsigned)sy < 64u && (unsigned)sx < 64u) {
                float4 v = *(const float4*)(Vb + (size_t)((sy << 6) + sx) * 64);
                ax += v.x; ay += v.y; az += v.z; aw += v.w;
            }
        }
    }
    float* Tb = T_out + ((size_t)b * 64 + cg * 16 + cq * 4) * HW + (y << 6) + x;
    Tb[0]          = ax * (1.f / 9.f);
    Tb[HW]         = ay * (1.f / 9.f);
    Tb[2 * HW]     = az * (1.f / 9.f);
    Tb[3 * HW]     = aw * (1.f / 9.f);
}

extern "C" void kernel_launch(void* const* d_in, const int* in_sizes, int n_in,
                              void* d_out, int out_size, void* d_ws, size_t ws_size,
                              hipStream_t stream) {
    const float* V = (const float*)d_in[0];
    const float* K = (const float*)d_in[1];
    const float* Q = (const float*)d_in[2];
    float* S_out = (float*)d_out;            // 4*4096
    float* T_out = S_out + 4 * HW;           // 4*64*4096

    char* ws = (char*)d_ws;
    float* pix2q = (float*)(ws + 0);                 // 64 KB
    float* pix2k = (float*)(ws + 65536);             // 64 KB
    float* part_val = (float*)(ws + 262144);         // 4*32*4096 f = 2 MB used
    int*   argF  = (int*)(ws + 4456448);             // 64 KB
    int*   part_arg = (int*)(ws + 8650752);          // 2 MB used
    float* VT    = (float*)(ws + 10747904);          // 4*4096*64 f32 = 4 MiB
    unsigned short* Aq = (unsigned short*)(ws + 17039360);   // 4*4096*192 bf16 = 6 MiB
    unsigned short* Bq = (unsigned short*)(ws + 23330816);   // 6 MiB

    prep_kernel<<<dim3(64, 4, 3), 256, 0, stream>>>(Q, K, V, Aq, Bq, VT, pix2q, pix2k);
    gemm_fused_kernel<<<dim3(32, 32, 4), 512, 0, stream>>>(Aq, Bq, pix2k, part_val, part_arg);
    argcombine_kernel<<<dim3(64, 4), 256, 0, stream>>>(part_val, part_arg, pix2q, S_out, argF);
    gatherT_kernel<<<dim3(64, 4, 4), 256, 0, stream>>>(VT, argF, T_out);
}

// Round 13
// 186.857 us; speedup vs baseline: 1.3261x; 1.0195x over previous
//
#include <hip/hip_runtime.h>
#include <math.h>

#define HW 4096   // H*W = 64*64; B=4, C=64, H=W=64, L=4096

typedef short bf16x8 __attribute__((ext_vector_type(8)));
typedef float floatx4 __attribute__((ext_vector_type(4)));
typedef unsigned short u16x8 __attribute__((ext_vector_type(8)));

__device__ __forceinline__ unsigned short f2bf_rne(float x) {
    unsigned int u = __float_as_uint(x);
    unsigned int r = (u + 0x7FFFu + ((u >> 16) & 1u)) >> 16;
    return (unsigned short)r;
}
__device__ __forceinline__ float bf2f(unsigned short h) {
    return __uint_as_float(((unsigned int)h) << 16);
}

// async global->LDS, 16 B per lane; LDS dest is wave-uniform base + lane*16.
__device__ __forceinline__ void gload_lds16(const void* gptr, void* lptr) {
    auto g = (const __attribute__((address_space(1))) unsigned int*)(unsigned long long)(gptr);
    auto l = (__attribute__((address_space(3))) unsigned int*)(unsigned int)(unsigned long long)(lptr);
    __builtin_amdgcn_global_load_lds(g, l, 16, 0, 0);
}

// ---------------- prep: z=0 Q / z=1 K: split fp32 -> bf16 (hi,lo), transpose
// to [p][c], fused per-pixel squared norms. Row layout (192 shorts):
//   Aq[b][p] = [Qh | UNINIT | Ql],  Bq[b][p] = [Kh | Kl | UNINIT]
// (readers use only A slices {0,2} / B slices {0,1}).
// z=2: transpose V -> VT[b][p][c] (f32) so gatherT reads channels contiguous.
__global__ __launch_bounds__(256)
void prep_kernel(const float* __restrict__ Q, const float* __restrict__ K,
                 const float* __restrict__ V,
                 unsigned short* __restrict__ Aq, unsigned short* __restrict__ Bq,
                 float* __restrict__ VT,
                 float* __restrict__ pix2q, float* __restrict__ pix2k) {
    __shared__ float sT[64][65];
    const int tid = threadIdx.x;
    const int p0 = blockIdx.x * 64;
    const int b = blockIdx.y;
    const int which = blockIdx.z;            // 0=Q, 1=K, 2=V
    const float* __restrict__ src = (which == 0) ? Q : ((which == 1) ? K : V);

#pragma unroll
    for (int it = 0; it < 16; ++it) {
        int idx = it * 256 + tid;
        int c = idx >> 6, x = idx & 63;
        sT[c][x] = src[((size_t)b * 64 + c) * HW + p0 + x];
    }
    __syncthreads();
    const int pp = tid >> 2, qt = tid & 3;

    if (which == 2) {                        // V: pure f32 transpose
        float* dst = VT + ((size_t)b * 4096 + p0 + pp) * 64 + qt * 16;
#pragma unroll
        for (int j = 0; j < 4; ++j) {
            float4 v = make_float4(sT[qt * 16 + 4 * j + 0][pp], sT[qt * 16 + 4 * j + 1][pp],
                                   sT[qt * 16 + 4 * j + 2][pp], sT[qt * 16 + 4 * j + 3][pp]);
            *(float4*)(dst + 4 * j) = v;
        }
        return;
    }

    const int isK = which;
    unsigned short* __restrict__ dst = isK ? Bq : Aq;
    float* __restrict__ pix2 = isK ? pix2k : pix2q;
    const size_t base = ((size_t)b * 4096 + p0 + pp) * 192;
    {
        float sq = 0.f;
        u16x8 hv[2], lv[2];
#pragma unroll
        for (int g = 0; g < 2; ++g)
#pragma unroll
            for (int j = 0; j < 8; ++j) {
                int c = qt * 16 + g * 8 + j;
                float x = sT[c][pp];
                sq = fmaf(x, x, sq);
                unsigned short h = f2bf_rne(x);
                hv[g][j] = h;
                lv[g][j] = f2bf_rne(x - bf2f(h));
            }
        sq += __shfl_xor(sq, 1, 64);
        sq += __shfl_xor(sq, 2, 64);
        if (qt == 0) pix2[(b << 12) + p0 + pp] = sq;
#pragma unroll
        for (int g = 0; g < 2; ++g) {
            int co = qt * 16 + g * 8;
            *(u16x8*)(dst + base + co)                     = hv[g];  // hi slice
            *(u16x8*)(dst + base + (isK ? 64 : 128) + co)  = lv[g];  // lo slice
        }
    }
}

// ---------------- fused MFMA GEMM (K=576: y-3sum in K) + x-3sum + argmax -----
// 128x128 tile, 8 waves (512 thr), wave tile 64(q) x 32(k): acc = 32 regs.
// 3 mega-steps (one per dy); per kk: all 12 frag ds_reads issue UP FRONT
// (first MM8 gated on its 6 via lgkmcnt; the rest arrive under MFMA), then
// s0=Qh.Kh, s1=Qh.Kl, s2=Ql.Kh with distinct temp arrays (no false deps);
// kk fully unrolled so the pressure-aware scheduler overlaps kk1 loads with
// kk0 MFMAs up to the 128-reg cap. Kh'/Al-unused never staged.
// Rings: A 5 slots {Ah0@0,Ah1@1,Ah2@4,Ah3@2; Al0@2,Al1@3,Al2@0,Al3@3},
//        B 5 slots {Bh0@0,Bh1@1,Bh2@4,Bh3@2; Bl0@2,Bl1@3,Bl2@0,Bl3@3}.
// Counted-vmcnt ring schedule hand-verified (R12); the 9 early pix2k loads
// are OLDER than all gloads so every counted wait also retires them.
#define WAITV(n_) asm volatile("s_waitcnt vmcnt(" #n_ ")" ::: "memory")
#define PBAR(n_) do { WAITV(n_); __builtin_amdgcn_s_barrier(); \
                      asm volatile("" ::: "memory"); } while (0)
#define SB do { __builtin_amdgcn_s_barrier(); asm volatile("" ::: "memory"); } while (0)

#define ISSUE_A(c_, sg_, slot_) \
    gload_lds16(agb + (size_t)((c_) * 64 + rr) * 384 + (sg_) * 128 + G16, \
                smem + (slot_) * 8192 + t16)
#define ISSUE_B(c_, sg_, slot_) \
    gload_lds16(bgb + (size_t)((c_) * 64 + rr) * 384 + (sg_) * 128 + G16, \
                smemB + (slot_) * 8192 + t16)

#define GISS_A(c_, sg_, slot_) do { \
    uint4 v_ = make_uint4(0u, 0u, 0u, 0u); \
    if ((unsigned)(arow + (c_) * 64 + rr) < 4096u) \
        v_ = *(const uint4*)(agb + (ptrdiff_t)((c_) * 64 + rr) * 384 + (sg_) * 128 + G16); \
    *(uint4*)(smem + (slot_) * 8192 + t16) = v_; \
} while (0)
#define GISS_B(c_, sg_, slot_) do { \
    uint4 v_ = make_uint4(0u, 0u, 0u, 0u); \
    if ((unsigned)(brow + (c_) * 64 + rr) < 4096u) \
        v_ = *(const uint4*)(bgb + (ptrdiff_t)((c_) * 64 + rr) * 384 + (sg_) * 128 + G16); \
    *(uint4*)(smemB + (slot_) * 8192 + t16) = v_; \
} while (0)

#define MM8(af_, bf_) do { \
    _Pragma("unroll") \
    for (int mt_ = 0; mt_ < 4; ++mt_) \
        _Pragma("unroll") \
        for (int nt_ = 0; nt_ < 2; ++nt_) \
            acc[mt_][nt_] = __builtin_amdgcn_mfma_f32_16x16x32_bf16( \
                (af_)[mt_], (bf_)[nt_], acc[mt_][nt_], 0, 0, 0); \
} while (0)

#define DY_MEGA(dy_) do { \
    const char* AhS_ = smem + ahS[wm + (dy_)] * 8192 + rowB; \
    const char* AlS_ = smem + alS[wm + (dy_)] * 8192 + rowB; \
    const char* BhS_ = smemB + bhS[wnC + (dy_)] * 8192 + rowBB; \
    const char* BlS_ = smemB + blS[wnC + (dy_)] * 8192 + rowBB; \
    _Pragma("unroll") \
    for (int kk = 0; kk < 2; ++kk) { \
        const int pk_ = kk ? posK1 : posK0; \
        bf16x8 afc[4], bfc[2], bl2[2], al4[4]; \
        _Pragma("unroll") \
        for (int mt = 0; mt < 4; ++mt) \
            afc[mt] = *(const bf16x8*)(AhS_ + mt * 2048 + pk_); \
        _Pragma("unroll") \
        for (int nt = 0; nt < 2; ++nt) \
            bfc[nt] = *(const bf16x8*)(BhS_ + nt * 2048 + pk_); \
        _Pragma("unroll") \
        for (int nt = 0; nt < 2; ++nt) \
            bl2[nt] = *(const bf16x8*)(BlS_ + nt * 2048 + pk_); \
        _Pragma("unroll") \
        for (int mt = 0; mt < 4; ++mt) \
            al4[mt] = *(const bf16x8*)(AlS_ + mt * 2048 + pk_); \
        __builtin_amdgcn_s_setprio(1); \
        MM8(afc, bfc); \
        MM8(afc, bl2); \
        MM8(al4, bfc); \
        __builtin_amdgcn_s_setprio(0); \
    } \
} while (0)

__global__ __launch_bounds__(512, 4)
void gemm_fused_kernel(const unsigned short* __restrict__ Aq, const unsigned short* __restrict__ Bq,
                       const float* __restrict__ pix2k,
                       float* __restrict__ part_val, int* __restrict__ part_arg) {
    __shared__ __align__(16) char smem[81920];   // A 5x8K | B 5x8K; epilogue aliases A region
    char* const smemB = smem + 40960;
    const int tid = threadIdx.x;
    const int lane = tid & 63, wid = tid >> 6;
    const int m15 = lane & 15, quad = lane >> 4;
    const int wm = wid & 1;                  // q half (64 rows)
    const int wn2 = wid >> 1;                // k quarter (32 cols), 0..3
    const int wnC = wn2 >> 1, wnF = wn2 & 1; // B chunk half / frag pair
    // chunk -> slot maps (see header comment)
    const int ahS[4] = {0, 1, 4, 2};
    const int alS[4] = {2, 3, 0, 3};
    const int bhS[4] = {0, 1, 4, 2};
    const int blS[4] = {2, 3, 0, 3};
    // XCD-chunked swizzle: per-b 1024 wgs; XCD x owns 4 q-tiles x 32 k-tiles.
    const int f = blockIdx.x + (blockIdx.y << 5);
    const int o = ((f & 7) << 7) + (f >> 3);
    const int kt = o & 31, qt = o >> 5;
    const int k0 = kt << 7;
    const int q0 = qt << 7;
    const int b = blockIdx.z;
    const int arow = q0 - 64, brow = k0 - 64;
    const char* agb = (const char*)(Aq + (size_t)b * 4096 * 192) + (ptrdiff_t)arow * 384;
    const char* bgb = (const char*)(Bq + (size_t)b * 4096 * 192) + (ptrdiff_t)brow * 384;
    const bool aInt = (q0 >= 64) && (q0 <= 4096 - 192);
    const bool bInt = (k0 >= 64) && (k0 <= 4096 - 192);

    // staging: 512 thr x 16 B = one 8 KB chunk per issue (1 gload/thread)
    const int rr = tid >> 3;
    const int G16 = ((tid & 7) ^ (rr & 7)) * 16;
    const int t16 = tid * 16;
    // fragment-read offsets (row&7 == m15&7 for all frag rows)
    const int rowB = m15 * 128;
    const int rowBB = (wnF * 32 + m15) * 128;
    const int posK0 = (quad ^ (m15 & 7)) * 16;
    const int posK1 = ((4 + quad) ^ (m15 & 7)) * 16;

    // early rnk inputs: 9 pix2k loads issued BEFORE staging; results unused
    // until the epilogue, so no wait here; being oldest, all counted waits
    // retire them (waves without loads just count fewer -- both safe).
    float pk9[9];
    if (tid < 128) {
        int k = k0 + tid;
        int py = k >> 6, px = k & 63;
#pragma unroll
        for (int t = 0; t < 9; ++t) {
            int yy = py + t / 3 - 1, xx = px + t % 3 - 1;
            pk9[t] = ((unsigned)yy < 64u && (unsigned)xx < 64u)
                   ? pix2k[(b << 12) + (yy << 6) + xx] : 0.f;
        }
    } else {
#pragma unroll
        for (int t = 0; t < 9; ++t) pk9[t] = 0.f;
    }

    floatx4 acc[4][2];
#pragma unroll
    for (int i = 0; i < 4; ++i)
#pragma unroll
        for (int j = 0; j < 2; ++j) acc[i][j] = (floatx4)0.f;

    if (aInt && bInt) {
        // prologue (10 chunks): Ah0@0 Ah1@1 Bh0@0 Bh1@1 Al0@2 Al1@3 Bl0@2
        // Bl1@3 Ah2@4 Bh2@4
        ISSUE_A(0, 0, 0); ISSUE_A(1, 0, 1); ISSUE_B(0, 0, 0); ISSUE_B(1, 0, 1);
        ISSUE_A(0, 2, 2); ISSUE_A(1, 2, 3); ISSUE_B(0, 1, 2); ISSUE_B(1, 1, 3);
        ISSUE_A(2, 0, 4); ISSUE_B(2, 0, 4);
        PBAR(2);                 // retire first 8 = dy0 working set (+ pix2k)
        DY_MEGA(0);
        SB;                      // dy0 readers done -> slots 0(A),0(B),2(A),2(B) free
        ISSUE_A(2, 2, 0);        // Al2 -> A slot 0
        ISSUE_B(2, 1, 0);        // Bl2 -> B slot 0
        ISSUE_A(3, 0, 2);        // Ah3 -> A slot 2
        ISSUE_B(3, 0, 2);        // Bh3 -> B slot 2
        PBAR(2);                 // retire Ah2,Bh2,Al2,Bl2 (Ah3,Bh3 in flight)
        DY_MEGA(1);
        SB;                      // dy1 readers done -> slots 3(A),3(B) free
        ISSUE_A(3, 2, 3);        // Al3 -> A slot 3
        ISSUE_B(3, 1, 3);        // Bl3 -> B slot 3
        PBAR(0);                 // retire Ah3,Bh3,Al3,Bl3
        DY_MEGA(2);
    } else {
        // guarded boundary path: same slots, predicated uint4 + ds_write
        GISS_A(0, 0, 0); GISS_A(1, 0, 1); GISS_B(0, 0, 0); GISS_B(1, 0, 1);
        GISS_A(0, 2, 2); GISS_A(1, 2, 3); GISS_B(0, 1, 2); GISS_B(1, 1, 3);
        GISS_A(2, 0, 4); GISS_B(2, 0, 4);
        __syncthreads();
        DY_MEGA(0);
        __syncthreads();
        GISS_A(2, 2, 0); GISS_B(2, 1, 0); GISS_A(3, 0, 2); GISS_B(3, 0, 2);
        __syncthreads();
        DY_MEGA(1);
        __syncthreads();
        GISS_A(3, 2, 3); GISS_B(3, 1, 3);
        __syncthreads();
        DY_MEGA(2);
    }
    __syncthreads();   // rings dead before epilogue overwrites

    // ---- epilogue: Lrnk from preloaded pk9 (pure ALU); two 64-row phases;
    // x-3sum + argmax over the 128-k tile; cross-wave LDS reduce -> one
    // partial per (block, q) ----
    float* Csh = (float*)smem;               // [64][133] = 34048 B
    float* bvs = (float*)(smem + 34816);     // [8][64]
    int*   bas = (int*)(smem + 36864);       // [8][64]
    float* Lrnk = (float*)(smem + 38912);    // [128]
    if (tid < 128) {
        float sk = 0.f;
#pragma unroll
        for (int t = 0; t < 9; ++t) sk += pk9[t];
        Lrnk[tid] = 1.f / fmaxf(sqrtf(sk), 1e-12f);
    }
    const int q_l = tid & 63;
    const int qr = tid >> 6;                 // k-eighth (0..7), one per wave
    const int c0 = qr * 16;
    const float4 zero4 = make_float4(0.f, 0.f, 0.f, 0.f);

#pragma unroll
    for (int h = 0; h < 2; ++h) {
        if (h) __syncthreads();              // phase-0 readers done before overwrite
        if (wm == h) {
#pragma unroll
            for (int mt = 0; mt < 4; ++mt)
#pragma unroll
                for (int nt = 0; nt < 2; ++nt)
#pragma unroll
                    for (int j = 0; j < 4; ++j)
                        Csh[(mt * 16 + quad * 4 + j) * 133 + (wn2 << 5) + nt * 16 + m15] =
                            acc[mt][nt][j];
        }
        __syncthreads();                     // also orders Lrnk writes (h==0)

        const bool qm = q_l > 0;             // qx>0: diag- allowed
        const bool qp = q_l < 63;            // qx<63: diag+ allowed
        const float* rC = Csh + q_l * 133;
        const float* rM = Csh + (q_l - 1) * 133;
        const float* rP = Csh + (q_l + 1) * 133;
        float4 prevm = (qm && c0 > 0) ? *(const float4*)&rM[c0 - 4] : zero4;
        float4 rpj   = qp ? *(const float4*)&rP[c0] : zero4;
        float bv = -INFINITY;
        int ba = 0;
#pragma unroll
        for (int j = 0; j < 4; ++j) {
            int c = c0 + 4 * j;
            float4 cen = *(const float4*)&rC[c];
            float4 rm4 = qm ? *(const float4*)&rM[c] : zero4;
            float4 rp1 = (qp && (c + 4) < 128) ? *(const float4*)&rP[c + 4] : zero4;
            float4 o4;
            o4.x = cen.x + (((c & 63) != 0) ? prevm.w : 0.f) + rpj.y;
            o4.y = cen.y + rm4.x + rpj.z;
            o4.z = cen.z + rm4.y + rpj.w;
            o4.w = cen.w + rm4.z + ((((c + 3) & 63) != 63) ? rp1.x : 0.f);
            float4 rk = *(const float4*)&Lrnk[c];
            // ascending k + strict > = first-occurrence argmax
            float v0 = o4.x * rk.x; if (v0 > bv) { bv = v0; ba = k0 + c + 0; }
            float v1 = o4.y * rk.y; if (v1 > bv) { bv = v1; ba = k0 + c + 1; }
            float v2 = o4.z * rk.z; if (v2 > bv) { bv = v2; ba = k0 + c + 2; }
            float v3 = o4.w * rk.w; if (v3 > bv) { bv = v3; ba = k0 + c + 3; }
            prevm = rm4;
            rpj = rp1;
        }
        bvs[(qr << 6) + q_l] = bv;
        bas[(qr << 6) + q_l] = ba;
        __syncthreads();
        if (tid < 64) {
            float v = bvs[tid];
            int a = bas[tid];
#pragma unroll
            for (int s = 1; s < 8; ++s) {    // ascending eighth = ascending k
                float v2 = bvs[(s << 6) + tid];
                if (v2 > v) { v = v2; a = bas[(s << 6) + tid]; }
            }
            int q = q0 + h * 64 + tid;
            part_val[(((b << 5) + kt) << 12) + q] = v;
            part_arg[(((b << 5) + kt) << 12) + q] = a;
        }
    }
}

// ---------------- combine 32 k-slot partials -> final arg + S ----------------
__global__ __launch_bounds__(256)
void argcombine_kernel(const float* __restrict__ part_val, const int* __restrict__ part_arg,
                       const float* __restrict__ pix2q,
                       float* __restrict__ S_out, int* __restrict__ argF) {
    __shared__ float rv[4][64];
    __shared__ int ra[4][64];
    const int tid = threadIdx.x;
    const int qi = tid & 63, sg = tid >> 6;
    const int q = blockIdx.x * 64 + qi;
    const int b = blockIdx.y;
    const int base = (b << 17) + q;
    float bv = -INFINITY; int ba = 0;
#pragma unroll
    for (int i = 0; i < 8; ++i) {            // ascending s = ascending k
        int s = sg * 8 + i;
        float v = part_val[base + (s << 12)];
        int aa = part_arg[base + (s << 12)];
        if (v > bv) { bv = v; ba = aa; }
    }
    rv[sg][qi] = bv; ra[sg][qi] = ba;
    __syncthreads();
    if (tid < 64) {
        float v = rv[0][tid]; int a = ra[0][tid];
#pragma unroll
        for (int s = 1; s < 4; ++s) {        // ascending group: first max wins
            float v2 = rv[s][tid];
            if (v2 > v) { v = v2; a = ra[s][tid]; }
        }
        int py = blockIdx.x, px = tid;       // q = py*64 + px
        float sq = 0.f;
        for (int dy = -1; dy <= 1; ++dy)
            for (int dx = -1; dx <= 1; ++dx) {
                int y2 = py + dy, x2 = px + dx;
                if ((unsigned)y2 < 64u && (unsigned)x2 < 64u)
                    sq += pix2q[(b << 12) + (y2 << 6) + x2];
            }
        int idx = (b << 12) + (py << 6) + px;
        S_out[idx] = v * (1.f / fmaxf(sqrtf(sq), 1e-12f));
        argF[idx] = a;
    }
}

// ---------------- gather + fold: T[c,y,x] = (1/9) sum_9 VT[a(q)+d][c] --------
__global__ __launch_bounds__(256)
void gatherT_kernel(const float* __restrict__ VT, const int* __restrict__ argF,
                    float* __restrict__ T_out) {
    __shared__ int sArg[192];
    const int y = blockIdx.x, b = blockIdx.y, cg = blockIdx.z;
    const int tid = threadIdx.x;
    if (tid < 192) {
        int r = tid >> 6, x = tid & 63;
        int yy = y - 1 + r;
        sArg[tid] = ((unsigned)yy < 64u) ? argF[(b << 12) + (yy << 6) + x] : 0;
    }
    __syncthreads();

    const int x = tid >> 2, cq = tid & 3;
    const float* Vb = VT + (size_t)b * 4096 * 64 + cg * 16 + cq * 4;
    float ax = 0.f, ay = 0.f, az = 0.f, aw = 0.f;
#pragma unroll
    for (int t = 0; t < 9; ++t) {
        int dy = t / 3 - 1, dx = t % 3 - 1;
        int qy = y - dy, qx = x - dx;
        if ((unsigned)qy < 64u && (unsigned)qx < 64u) {
            int a = sArg[(1 - dy) * 64 + qx];
            int sy = (a >> 6) + dy, sx = (a & 63) + dx;
            if ((unsigned)sy < 64u && (unsigned)sx < 64u) {
                float4 v = *(const float4*)(Vb + (size_t)((sy << 6) + sx) * 64);
                ax += v.x; ay += v.y; az += v.z; aw += v.w;
            }
        }
    }
    float* Tb = T_out + ((size_t)b * 64 + cg * 16 + cq * 4) * HW + (y << 6) + x;
    Tb[0]          = ax * (1.f / 9.f);
    Tb[HW]         = ay * (1.f / 9.f);
    Tb[2 * HW]     = az * (1.f / 9.f);
    Tb[3 * HW]     = aw * (1.f / 9.f);
}

extern "C" void kernel_launch(void* const* d_in, const int* in_sizes, int n_in,
                              void* d_out, int out_size, void* d_ws, size_t ws_size,
                              hipStream_t stream) {
    const float* V = (const float*)d_in[0];
    const float* K = (const float*)d_in[1];
    const float* Q = (const float*)d_in[2];
    float* S_out = (float*)d_out;            // 4*4096
    float* T_out = S_out + 4 * HW;           // 4*64*4096

    char* ws = (char*)d_ws;
    float* pix2q = (float*)(ws + 0);                 // 64 KB
    float* pix2k = (float*)(ws + 65536);             // 64 KB
    float* part_val = (float*)(ws + 262144);         // 4*32*4096 f = 2 MB used
    int*   argF  = (int*)(ws + 4456448);             // 64 KB
    int*   part_arg = (int*)(ws + 8650752);          // 2 MB used
    float* VT    = (float*)(ws + 10747904);          // 4*4096*64 f32 = 4 MiB
    unsigned short* Aq = (unsigned short*)(ws + 17039360);   // 4*4096*192 bf16 = 6 MiB
    unsigned short* Bq = (unsigned short*)(ws + 23330816);   // 6 MiB

    prep_kernel<<<dim3(64, 4, 3), 256, 0, stream>>>(Q, K, V, Aq, Bq, VT, pix2q, pix2k);
    gemm_fused_kernel<<<dim3(32, 32, 4), 512, 0, stream>>>(Aq, Bq, pix2k, part_val, part_arg);
    argcombine_kernel<<<dim3(64, 4), 256, 0, stream>>>(part_val, part_arg, pix2q, S_out, argF);
    gatherT_kernel<<<dim3(64, 4, 4), 256, 0, stream>>>(VT, argF, T_out);
}

// Round 14
// 185.968 us; speedup vs baseline: 1.3324x; 1.0048x over previous
//
#include <hip/hip_runtime.h>
#include <math.h>

#define HW 4096   // H*W = 64*64; B=4, C=64, H=W=64, L=4096

typedef short bf16x8 __attribute__((ext_vector_type(8)));
typedef float floatx4 __attribute__((ext_vector_type(4)));
typedef unsigned short u16x8 __attribute__((ext_vector_type(8)));

__device__ __forceinline__ unsigned short f2bf_rne(float x) {
    unsigned int u = __float_as_uint(x);
    unsigned int r = (u + 0x7FFFu + ((u >> 16) & 1u)) >> 16;
    return (unsigned short)r;
}
__device__ __forceinline__ float bf2f(unsigned short h) {
    return __uint_as_float(((unsigned int)h) << 16);
}

// async global->LDS, 16 B per lane; LDS dest is wave-uniform base + lane*16.
__device__ __forceinline__ void gload_lds16(const void* gptr, void* lptr) {
    auto g = (const __attribute__((address_space(1))) unsigned int*)(unsigned long long)(gptr);
    auto l = (__attribute__((address_space(3))) unsigned int*)(unsigned int)(unsigned long long)(lptr);
    __builtin_amdgcn_global_load_lds(g, l, 16, 0, 0);
}

// ---------------- prep: z=0 Q / z=1 K: split fp32 -> bf16 (hi,lo), transpose
// to [p][c], fused per-pixel squared norms. Row layout (192 shorts):
//   Aq[b][p] = [Qh | UNINIT | Ql],  Bq[b][p] = [Kh | Kl | UNINIT]
// (readers use only A slices {0,2} / B slices {0,1}).
// z=2: transpose V -> VT[b][p][c] (f32) so gatherT reads channels contiguous.
__global__ __launch_bounds__(256)
void prep_kernel(const float* __restrict__ Q, const float* __restrict__ K,
                 const float* __restrict__ V,
                 unsigned short* __restrict__ Aq, unsigned short* __restrict__ Bq,
                 float* __restrict__ VT,
                 float* __restrict__ pix2q, float* __restrict__ pix2k) {
    __shared__ float sT[64][65];
    const int tid = threadIdx.x;
    const int p0 = blockIdx.x * 64;
    const int b = blockIdx.y;
    const int which = blockIdx.z;            // 0=Q, 1=K, 2=V
    const float* __restrict__ src = (which == 0) ? Q : ((which == 1) ? K : V);

#pragma unroll
    for (int it = 0; it < 16; ++it) {
        int idx = it * 256 + tid;
        int c = idx >> 6, x = idx & 63;
        sT[c][x] = src[((size_t)b * 64 + c) * HW + p0 + x];
    }
    __syncthreads();
    const int pp = tid >> 2, qt = tid & 3;

    if (which == 2) {                        // V: pure f32 transpose
        float* dst = VT + ((size_t)b * 4096 + p0 + pp) * 64 + qt * 16;
#pragma unroll
        for (int j = 0; j < 4; ++j) {
            float4 v = make_float4(sT[qt * 16 + 4 * j + 0][pp], sT[qt * 16 + 4 * j + 1][pp],
                                   sT[qt * 16 + 4 * j + 2][pp], sT[qt * 16 + 4 * j + 3][pp]);
            *(float4*)(dst + 4 * j) = v;
        }
        return;
    }

    const int isK = which;
    unsigned short* __restrict__ dst = isK ? Bq : Aq;
    float* __restrict__ pix2 = isK ? pix2k : pix2q;
    const size_t base = ((size_t)b * 4096 + p0 + pp) * 192;
    {
        float sq = 0.f;
        u16x8 hv[2], lv[2];
#pragma unroll
        for (int g = 0; g < 2; ++g)
#pragma unroll
            for (int j = 0; j < 8; ++j) {
                int c = qt * 16 + g * 8 + j;
                float x = sT[c][pp];
                sq = fmaf(x, x, sq);
                unsigned short h = f2bf_rne(x);
                hv[g][j] = h;
                lv[g][j] = f2bf_rne(x - bf2f(h));
            }
        sq += __shfl_xor(sq, 1, 64);
        sq += __shfl_xor(sq, 2, 64);
        if (qt == 0) pix2[(b << 12) + p0 + pp] = sq;
#pragma unroll
        for (int g = 0; g < 2; ++g) {
            int co = qt * 16 + g * 8;
            *(u16x8*)(dst + base + co)                     = hv[g];  // hi slice
            *(u16x8*)(dst + base + (isK ? 64 : 128) + co)  = lv[g];  // lo slice
        }
    }
}

// ---------------- fused MFMA GEMM (K=576: y-3sum in K) + x-3sum + argmax -----
// 128x128 tile, 4 waves (256 thr), wave tile 64(q) x 64(k): acc = 64 regs.
// (R12/R13's 8-wave 64x32 tiles cost 1.5x the LDS frag traffic; R12 proved
// the extra occupancy is worth ~0, so trade it back: 384 vs 576 ds_read_b128
// per block. Reg law: (256,2) cap 256; ~100 arch + 64 acc fits - R5 proved.)
// 3 mega-steps (one per dy); per kk: all 16 frag ds_reads issue UP FRONT,
// then s0=Qh.Kh, s1=Qh.Kl, s2=Ql.Kh as 3x16 MFMA with distinct temp arrays.
// Rings: A 5 slots {Ah0@0,Ah1@1,Ah2@4,Ah3@2; Al0@2,Al1@3,Al2@0,Al3@3},
//        B 5 slots {Bh0@0,Bh1@1,Bh2@4,Bh3@2; Bl0@2,Bl1@3,Bl2@0,Bl3@3}.
// Counted-vmcnt schedule re-derived for 2 loads/thread/chunk: PBAR(4)/(4)/(0);
// hazard table hand-verified (same chunk order as R12, counts doubled).
// 9 early pix2k loads are oldest -> every counted wait retires them.
#define WAITV(n_) asm volatile("s_waitcnt vmcnt(" #n_ ")" ::: "memory")
#define PBAR(n_) do { WAITV(n_); __builtin_amdgcn_s_barrier(); \
                      asm volatile("" ::: "memory"); } while (0)
#define SB do { __builtin_amdgcn_s_barrier(); asm volatile("" ::: "memory"); } while (0)

#define ISSUE_A(c_, sg_, slot_) do { \
    const char* g_ = agb + (size_t)((c_) * 64) * 384 + (sg_) * 128; \
    gload_lds16(g_ + g0off, smem + (slot_) * 8192 + l0off); \
    gload_lds16(g_ + g1off, smem + (slot_) * 8192 + l1off); \
} while (0)
#define ISSUE_B(c_, sg_, slot_) do { \
    const char* g_ = bgb + (size_t)((c_) * 64) * 384 + (sg_) * 128; \
    gload_lds16(g_ + g0off, smemB + (slot_) * 8192 + l0off); \
    gload_lds16(g_ + g1off, smemB + (slot_) * 8192 + l1off); \
} while (0)

#define GISS_A(c_, sg_, slot_) do { \
    const char* g_ = agb + (ptrdiff_t)((c_) * 64) * 384 + (sg_) * 128; \
    uint4 v0_ = make_uint4(0u, 0u, 0u, 0u), v1_ = v0_; \
    if ((unsigned)(arow + (c_) * 64 + rr0) < 4096u) \
        v0_ = *(const uint4*)(g_ + g0off); \
    if ((unsigned)(arow + (c_) * 64 + rr1) < 4096u) \
        v1_ = *(const uint4*)(g_ + g1off); \
    *(uint4*)(smem + (slot_) * 8192 + l0off) = v0_; \
    *(uint4*)(smem + (slot_) * 8192 + l1off) = v1_; \
} while (0)
#define GISS_B(c_, sg_, slot_) do { \
    const char* g_ = bgb + (ptrdiff_t)((c_) * 64) * 384 + (sg_) * 128; \
    uint4 v0_ = make_uint4(0u, 0u, 0u, 0u), v1_ = v0_; \
    if ((unsigned)(brow + (c_) * 64 + rr0) < 4096u) \
        v0_ = *(const uint4*)(g_ + g0off); \
    if ((unsigned)(brow + (c_) * 64 + rr1) < 4096u) \
        v1_ = *(const uint4*)(g_ + g1off); \
    *(uint4*)(smemB + (slot_) * 8192 + l0off) = v0_; \
    *(uint4*)(smemB + (slot_) * 8192 + l1off) = v1_; \
} while (0)

#define MM16(af_, bf_) do { \
    _Pragma("unroll") \
    for (int mt_ = 0; mt_ < 4; ++mt_) \
        _Pragma("unroll") \
        for (int nt_ = 0; nt_ < 4; ++nt_) \
            acc[mt_][nt_] = __builtin_amdgcn_mfma_f32_16x16x32_bf16( \
                (af_)[mt_], (bf_)[nt_], acc[mt_][nt_], 0, 0, 0); \
} while (0)

#define DY_MEGA(dy_) do { \
    const char* AhS_ = smem + ahS[wm + (dy_)] * 8192 + rowB; \
    const char* AlS_ = smem + alS[wm + (dy_)] * 8192 + rowB; \
    const char* BhS_ = smemB + bhS[wn + (dy_)] * 8192 + rowB; \
    const char* BlS_ = smemB + blS[wn + (dy_)] * 8192 + rowB; \
    _Pragma("unroll") \
    for (int kk = 0; kk < 2; ++kk) { \
        const int pk_ = kk ? posK1 : posK0; \
        bf16x8 afc[4], bh4[4], bl4[4], al4[4]; \
        _Pragma("unroll") \
        for (int mt = 0; mt < 4; ++mt) \
            afc[mt] = *(const bf16x8*)(AhS_ + mt * 2048 + pk_); \
        _Pragma("unroll") \
        for (int nt = 0; nt < 4; ++nt) \
            bh4[nt] = *(const bf16x8*)(BhS_ + nt * 2048 + pk_); \
        _Pragma("unroll") \
        for (int nt = 0; nt < 4; ++nt) \
            bl4[nt] = *(const bf16x8*)(BlS_ + nt * 2048 + pk_); \
        _Pragma("unroll") \
        for (int mt = 0; mt < 4; ++mt) \
            al4[mt] = *(const bf16x8*)(AlS_ + mt * 2048 + pk_); \
        __builtin_amdgcn_s_setprio(1); \
        MM16(afc, bh4); \
        MM16(afc, bl4); \
        MM16(al4, bh4); \
        __builtin_amdgcn_s_setprio(0); \
    } \
} while (0)

__global__ __launch_bounds__(256, 2)
void gemm_fused_kernel(const unsigned short* __restrict__ Aq, const unsigned short* __restrict__ Bq,
                       const float* __restrict__ pix2k,
                       float* __restrict__ part_val, int* __restrict__ part_arg) {
    __shared__ __align__(16) char smem[81920];   // A 5x8K | B 5x8K; epilogue aliases A region
    char* const smemB = smem + 40960;
    const int tid = threadIdx.x;
    const int lane = tid & 63, wid = tid >> 6;
    const int m15 = lane & 15, quad = lane >> 4;
    const int wm = wid & 1, wn = wid >> 1;   // wave grid: 2(q) x 2(k)
    // chunk -> slot maps
    const int ahS[4] = {0, 1, 4, 2};
    const int alS[4] = {2, 3, 0, 3};
    const int bhS[4] = {0, 1, 4, 2};
    const int blS[4] = {2, 3, 0, 3};
    // XCD-chunked swizzle: per-b 1024 wgs; XCD x owns 4 q-tiles x 32 k-tiles.
    const int f = blockIdx.x + (blockIdx.y << 5);
    const int o = ((f & 7) << 7) + (f >> 3);
    const int kt = o & 31, qt = o >> 5;
    const int k0 = kt << 7;
    const int q0 = qt << 7;
    const int b = blockIdx.z;
    const int arow = q0 - 64, brow = k0 - 64;
    const char* agb = (const char*)(Aq + (size_t)b * 4096 * 192) + (ptrdiff_t)arow * 384;
    const char* bgb = (const char*)(Bq + (size_t)b * 4096 * 192) + (ptrdiff_t)brow * 384;
    const bool aInt = (q0 >= 64) && (q0 <= 4096 - 192);
    const bool bInt = (k0 >= 64) && (k0 <= 4096 - 192);

    // staging: 256 thr x 2 x 16 B = one 8 KB chunk per ISSUE (2 gloads/thread)
    const int rr0 = tid >> 3, ps = tid & 7;
    const int g0off = rr0 * 384 + (ps ^ (rr0 & 7)) * 16;
    const int l0off = tid * 16;
    const int rr1 = (256 + tid) >> 3;
    const int g1off = rr1 * 384 + (ps ^ (rr1 & 7)) * 16;
    const int l1off = (256 + tid) * 16;
    // fragment-read offsets (row&7 == m15&7 for all frag rows)
    const int rowB = m15 * 128;
    const int posK0 = (quad ^ (m15 & 7)) * 16;
    const int posK1 = ((4 + quad) ^ (m15 & 7)) * 16;

    // early rnk inputs: 9 pix2k loads BEFORE staging (oldest -> retired by
    // every counted wait); results unused until the epilogue.
    float pk9[9];
    if (tid < 128) {
        int k = k0 + tid;
        int py = k >> 6, px = k & 63;
#pragma unroll
        for (int t = 0; t < 9; ++t) {
            int yy = py + t / 3 - 1, xx = px + t % 3 - 1;
            pk9[t] = ((unsigned)yy < 64u && (unsigned)xx < 64u)
                   ? pix2k[(b << 12) + (yy << 6) + xx] : 0.f;
        }
    } else {
#pragma unroll
        for (int t = 0; t < 9; ++t) pk9[t] = 0.f;
    }

    floatx4 acc[4][4];
#pragma unroll
    for (int i = 0; i < 4; ++i)
#pragma unroll
        for (int j = 0; j < 4; ++j) acc[i][j] = (floatx4)0.f;

    if (aInt && bInt) {
        // prologue (10 chunks, 20 loads/thread): Ah0@0 Ah1@1 Bh0@0 Bh1@1
        // Al0@2 Al1@3 Bl0@2 Bl1@3 Ah2@4 Bh2@4
        ISSUE_A(0, 0, 0); ISSUE_A(1, 0, 1); ISSUE_B(0, 0, 0); ISSUE_B(1, 0, 1);
        ISSUE_A(0, 2, 2); ISSUE_A(1, 2, 3); ISSUE_B(0, 1, 2); ISSUE_B(1, 1, 3);
        ISSUE_A(2, 0, 4); ISSUE_B(2, 0, 4);
        PBAR(4);                 // retire first 8 chunks = dy0 set (+ pix2k)
        DY_MEGA(0);
        SB;                      // dy0 readers done -> slots 0(A),0(B),2(A),2(B) free
        ISSUE_A(2, 2, 0);        // Al2 -> A slot 0
        ISSUE_B(2, 1, 0);        // Bl2 -> B slot 0
        ISSUE_A(3, 0, 2);        // Ah3 -> A slot 2
        ISSUE_B(3, 0, 2);        // Bh3 -> B slot 2
        PBAR(4);                 // retire Ah2,Bh2,Al2,Bl2 (Ah3,Bh3 in flight)
        DY_MEGA(1);
        SB;                      // dy1 readers done -> slots 3(A),3(B) free
        ISSUE_A(3, 2, 3);        // Al3 -> A slot 3
        ISSUE_B(3, 1, 3);        // Bl3 -> B slot 3
        PBAR(0);                 // retire Ah3,Bh3,Al3,Bl3
        DY_MEGA(2);
    } else {
        // guarded boundary path: same slots, predicated uint4 + ds_write
        GISS_A(0, 0, 0); GISS_A(1, 0, 1); GISS_B(0, 0, 0); GISS_B(1, 0, 1);
        GISS_A(0, 2, 2); GISS_A(1, 2, 3); GISS_B(0, 1, 2); GISS_B(1, 1, 3);
        GISS_A(2, 0, 4); GISS_B(2, 0, 4);
        __syncthreads();
        DY_MEGA(0);
        __syncthreads();
        GISS_A(2, 2, 0); GISS_B(2, 1, 0); GISS_A(3, 0, 2); GISS_B(3, 0, 2);
        __syncthreads();
        DY_MEGA(1);
        __syncthreads();
        GISS_A(3, 2, 3); GISS_B(3, 1, 3);
        __syncthreads();
        DY_MEGA(2);
    }
    __syncthreads();   // rings dead before epilogue overwrites

    // ---- epilogue: Lrnk from preloaded pk9 (pure ALU); two 64-row phases;
    // x-3sum + argmax over the 128-k tile; cross-wave LDS reduce -> one
    // partial per (block, q) ----
    float* Csh = (float*)smem;               // [64][133] = 34048 B
    float* bvs = (float*)(smem + 34816);     // [4][64]
    int*   bas = (int*)(smem + 35840);       // [4][64]
    float* Lrnk = (float*)(smem + 36864);    // [128]
    if (tid < 128) {
        float sk = 0.f;
#pragma unroll
        for (int t = 0; t < 9; ++t) sk += pk9[t];
        Lrnk[tid] = 1.f / fmaxf(sqrtf(sk), 1e-12f);
    }
    const int q_l = tid & 63;
    const int qr = tid >> 6;                 // k-quarter (0..3), one per wave
    const int c0 = qr * 32;
    const float4 zero4 = make_float4(0.f, 0.f, 0.f, 0.f);

#pragma unroll
    for (int h = 0; h < 2; ++h) {
        if (h) __syncthreads();              // phase-0 readers done before overwrite
        if (wm == h) {
#pragma unroll
            for (int mt = 0; mt < 4; ++mt)
#pragma unroll
                for (int nt = 0; nt < 4; ++nt)
#pragma unroll
                    for (int j = 0; j < 4; ++j)
                        Csh[(mt * 16 + quad * 4 + j) * 133 + wn * 64 + nt * 16 + m15] =
                            acc[mt][nt][j];
        }
        __syncthreads();                     // also orders Lrnk writes (h==0)

        const bool qm = q_l > 0;             // qx>0: diag- allowed
        const bool qp = q_l < 63;            // qx<63: diag+ allowed
        const float* rC = Csh + q_l * 133;
        const float* rM = Csh + (q_l - 1) * 133;
        const float* rP = Csh + (q_l + 1) * 133;
        float4 prevm = (qm && c0 > 0) ? *(const float4*)&rM[c0 - 4] : zero4;
        float4 rpj   = qp ? *(const float4*)&rP[c0] : zero4;
        float bv = -INFINITY;
        int ba = 0;
#pragma unroll
        for (int j = 0; j < 8; ++j) {
            int c = c0 + 4 * j;
            float4 cen = *(const float4*)&rC[c];
            float4 rm4 = qm ? *(const float4*)&rM[c] : zero4;
            float4 rp1 = (qp && (c + 4) < 128) ? *(const float4*)&rP[c + 4] : zero4;
            float4 o4;
            o4.x = cen.x + (((c & 63) != 0) ? prevm.w : 0.f) + rpj.y;
            o4.y = cen.y + rm4.x + rpj.z;
            o4.z = cen.z + rm4.y + rpj.w;
            o4.w = cen.w + rm4.z + ((((c + 3) & 63) != 63) ? rp1.x : 0.f);
            float4 rk = *(const float4*)&Lrnk[c];
            // ascending k + strict > = first-occurrence argmax
            float v0 = o4.x * rk.x; if (v0 > bv) { bv = v0; ba = k0 + c + 0; }
            float v1 = o4.y * rk.y; if (v1 > bv) { bv = v1; ba = k0 + c + 1; }
            float v2 = o4.z * rk.z; if (v2 > bv) { bv = v2; ba = k0 + c + 2; }
            float v3 = o4.w * rk.w; if (v3 > bv) { bv = v3; ba = k0 + c + 3; }
            prevm = rm4;
            rpj = rp1;
        }
        bvs[(qr << 6) + q_l] = bv;
        bas[(qr << 6) + q_l] = ba;
        __syncthreads();
        if (tid < 64) {
            float v = bvs[tid];
            int a = bas[tid];
#pragma unroll
            for (int s = 1; s < 4; ++s) {    // ascending quarter = ascending k
                float v2 = bvs[(s << 6) + tid];
                if (v2 > v) { v = v2; a = bas[(s << 6) + tid]; }
            }
            int q = q0 + h * 64 + tid;
            part_val[(((b << 5) + kt) << 12) + q] = v;
            part_arg[(((b << 5) + kt) << 12) + q] = a;
        }
    }
}

// ---------------- combine 32 k-slot partials -> final arg + S ----------------
__global__ __launch_bounds__(256)
void argcombine_kernel(const float* __restrict__ part_val, const int* __restrict__ part_arg,
                       const float* __restrict__ pix2q,
                       float* __restrict__ S_out, int* __restrict__ argF) {
    __shared__ float rv[4][64];
    __shared__ int ra[4][64];
    const int tid = threadIdx.x;
    const int qi = tid & 63, sg = tid >> 6;
    const int q = blockIdx.x * 64 + qi;
    const int b = blockIdx.y;
    const int base = (b << 17) + q;
    float bv = -INFINITY; int ba = 0;
#pragma unroll
    for (int i = 0; i < 8; ++i) {            // ascending s = ascending k
        int s = sg * 8 + i;
        float v = part_val[base + (s << 12)];
        int aa = part_arg[base + (s << 12)];
        if (v > bv) { bv = v; ba = aa; }
    }
    rv[sg][qi] = bv; ra[sg][qi] = ba;
    __syncthreads();
    if (tid < 64) {
        float v = rv[0][tid]; int a = ra[0][tid];
#pragma unroll
        for (int s = 1; s < 4; ++s) {        // ascending group: first max wins
            float v2 = rv[s][tid];
            if (v2 > v) { v = v2; a = ra[s][tid]; }
        }
        int py = blockIdx.x, px = tid;       // q = py*64 + px
        float sq = 0.f;
        for (int dy = -1; dy <= 1; ++dy)
            for (int dx = -1; dx <= 1; ++dx) {
                int y2 = py + dy, x2 = px + dx;
                if ((unsigned)y2 < 64u && (unsigned)x2 < 64u)
                    sq += pix2q[(b << 12) + (y2 << 6) + x2];
            }
        int idx = (b << 12) + (py << 6) + px;
        S_out[idx] = v * (1.f / fmaxf(sqrtf(sq), 1e-12f));
        argF[idx] = a;
    }
}

// ---------------- gather + fold: T[c,y,x] = (1/9) sum_9 VT[a(q)+d][c] --------
__global__ __launch_bounds__(256)
void gatherT_kernel(const float* __restrict__ VT, const int* __restrict__ argF,
                    float* __restrict__ T_out) {
    __shared__ int sArg[192];
    const int y = blockIdx.x, b = blockIdx.y, cg = blockIdx.z;
    const int tid = threadIdx.x;
    if (tid < 192) {
        int r = tid >> 6, x = tid & 63;
        int yy = y - 1 + r;
        sArg[tid] = ((unsigned)yy < 64u) ? argF[(b << 12) + (yy << 6) + x] : 0;
    }
    __syncthreads();

    const int x = tid >> 2, cq = tid & 3;
    const float* Vb = VT + (size_t)b * 4096 * 64 + cg * 16 + cq * 4;
    float ax = 0.f, ay = 0.f, az = 0.f, aw = 0.f;
#pragma unroll
    for (int t = 0; t < 9; ++t) {
        int dy = t / 3 - 1, dx = t % 3 - 1;
        int qy = y - dy, qx = x - dx;
        if ((unsigned)qy < 64u && (unsigned)qx < 64u) {
            int a = sArg[(1 - dy) * 64 + qx];
            int sy = (a >> 6) + dy, sx = (a & 63) + dx;
            if ((unsigned)sy < 64u && (unsigned)sx < 64u) {
                float4 v = *(const float4*)(Vb + (size_t)((sy << 6) + sx) * 64);
                ax += v.x; ay += v.y; az += v.z; aw += v.w;
            }
        }
    }
    float* Tb = T_out + ((size_t)b * 64 + cg * 16 + cq * 4) * HW + (y << 6) + x;
    Tb[0]          = ax * (1.f / 9.f);
    Tb[HW]         = ay * (1.f / 9.f);
    Tb[2 * HW]     = az * (1.f / 9.f);
    Tb[3 * HW]     = aw * (1.f / 9.f);
}

extern "C" void kernel_launch(void* const* d_in, const int* in_sizes, int n_in,
                              void* d_out, int out_size, void* d_ws, size_t ws_size,
                              hipStream_t stream) {
    const float* V = (const float*)d_in[0];
    const float* K = (const float*)d_in[1];
    const float* Q = (const float*)d_in[2];
    float* S_out = (float*)d_out;            // 4*4096
    float* T_out = S_out + 4 * HW;           // 4*64*4096

    char* ws = (char*)d_ws;
    float* pix2q = (float*)(ws + 0);                 // 64 KB
    float* pix2k = (float*)(ws + 65536);             // 64 KB
    float* part_val = (float*)(ws + 262144);         // 4*32*4096 f = 2 MB used
    int*   argF  = (int*)(ws + 4456448);             // 64 KB
    int*   part_arg = (int*)(ws + 8650752);          // 2 MB used
    float* VT    = (float*)(ws + 10747904);          // 4*4096*64 f32 = 4 MiB
    unsigned short* Aq = (unsigned short*)(ws + 17039360);   // 4*4096*192 bf16 = 6 MiB
    unsigned short* Bq = (unsigned short*)(ws + 23330816);   // 6 MiB

    prep_kernel<<<dim3(64, 4, 3), 256, 0, stream>>>(Q, K, V, Aq, Bq, VT, pix2q, pix2k);
    gemm_fused_kernel<<<dim3(32, 32, 4), 256, 0, stream>>>(Aq, Bq, pix2k, part_val, part_arg);
    argcombine_kernel<<<dim3(64, 4), 256, 0, stream>>>(part_val, part_arg, pix2q, S_out, argF);
    gatherT_kernel<<<dim3(64, 4, 4), 256, 0, stream>>>(VT, argF, T_out);
}